// Round 8
// baseline (32649.332 us; speedup 1.0000x reference)
//
#include <hip/hip_runtime.h>
#include <math.h>

#define SLEN 8192
#define DIM  256
#define H2N  256
#define G4   1024
#define NTAG 16
#define NEGV (-10000.0f)

// ws layout (float offsets unless noted)
#define OFF_PRE_F   0
#define OFF_PRE_B   (SLEN*G4)
#define OFF_HS_F    (2*SLEN*G4)
#define OFF_HS_B    (2*SLEN*G4 + SLEN*H2N)
#define OFF_FEATS   (2*SLEN*G4 + 2*SLEN*H2N)
#define OFF_MBOX    (OFF_FEATS + SLEN*NTAG)      // [f|b] x 2 buf x 256 u32
#define WS_NEEDED   ((size_t)(OFF_MBOX + 1024) * 4)

// ---------------- K1: pre = gather(emb, sentence[±]) @ w_ih^T + b ----------------
__global__ __launch_bounds__(256) void gemm_pre(
    const int* __restrict__ sent, const float* __restrict__ emb,
    const float* __restrict__ wf, const float* __restrict__ bf,
    const float* __restrict__ wb, const float* __restrict__ bb,
    float* __restrict__ pre_f, float* __restrict__ pre_b)
{
    const int dir = blockIdx.z;
    const float* w    = dir ? wb : wf;
    const float* bias = dir ? bb : bf;
    float* out        = dir ? pre_b : pre_f;
    const int m0 = blockIdx.x * 64, n0 = blockIdx.y * 64;

    __shared__ float As[16][68];   // [k][m]
    __shared__ float Bs[16][68];   // [k][n]
    __shared__ int   sidx[64];

    const int tid = threadIdx.x;
    const int tx = tid & 15, ty = tid >> 4;

    if (tid < 64) {
        int m = m0 + tid;
        int pos = dir ? (SLEN - 1 - m) : m;
        sidx[tid] = sent[pos];
    }
    __syncthreads();

    float acc[4][4];
#pragma unroll
    for (int i = 0; i < 4; i++)
#pragma unroll
        for (int j = 0; j < 4; j++) acc[i][j] = 0.f;

    const int lr = tid >> 2, lc = (tid & 3) * 4;

    for (int k0 = 0; k0 < DIM; k0 += 16) {
        float4 av = *(const float4*)(emb + (size_t)sidx[lr] * DIM + k0 + lc);
        float4 bv = *(const float4*)(w + (size_t)(n0 + lr) * DIM + k0 + lc);
        As[lc+0][lr] = av.x; As[lc+1][lr] = av.y; As[lc+2][lr] = av.z; As[lc+3][lr] = av.w;
        Bs[lc+0][lr] = bv.x; Bs[lc+1][lr] = bv.y; Bs[lc+2][lr] = bv.z; Bs[lc+3][lr] = bv.w;
        __syncthreads();
#pragma unroll
        for (int k = 0; k < 16; k++) {
            float4 a4 = *(const float4*)&As[k][ty * 4];
            float4 b4 = *(const float4*)&Bs[k][tx * 4];
            float a[4] = {a4.x, a4.y, a4.z, a4.w};
            float b[4] = {b4.x, b4.y, b4.z, b4.w};
#pragma unroll
            for (int i = 0; i < 4; i++)
#pragma unroll
                for (int j = 0; j < 4; j++) acc[i][j] += a[i] * b[j];
        }
        __syncthreads();
    }

    float4 b4 = *(const float4*)(bias + n0 + tx*4);
#pragma unroll
    for (int i = 0; i < 4; i++) {
        float4 v;
        v.x = acc[i][0] + b4.x; v.y = acc[i][1] + b4.y;
        v.z = acc[i][2] + b4.z; v.w = acc[i][3] + b4.w;
        *(float4*)(out + (size_t)(m0 + ty*4 + i) * G4 + n0 + tx*4) = v;
    }
}

__device__ __forceinline__ float fast_sigmoid(float x) {
    return 1.f / (1.f + __expf(-x));
}
__device__ __forceinline__ float fast_tanh(float x) {
    float xc = fminf(fmaxf(x, -15.f), 15.f);
    float e = __expf(2.f * xc);
    return (e - 1.f) / (e + 1.f);
}
__device__ __forceinline__ unsigned aload(const unsigned* p) {
    return __hip_atomic_load(p, __ATOMIC_RELAXED, __HIP_MEMORY_SCOPE_AGENT);
}
// single-wave LDS handoff fence (no vmcnt drain -> speculative loads survive)
__device__ __forceinline__ void lds_fence() {
    asm volatile("s_waitcnt lgkmcnt(0)" ::: "memory");
}

// ---------------- K2: fused bidirectional LSTM, 32 blocks, pipelined sync ----------------
// R7 analysis: sync RT (~store-visibility + 1-2 coherent-load RTs ~ 4,000 cy)
// was fully EXPOSED because the loop was dot->publish->wait. R8: each block
// owns 8 fwd + 8 bwd cells (the two chains are independent) and pipelines:
//   check_b -> dot_b/publish_b -> issue poll_b -> check_f -> dot_f/publish_f -> issue poll_f
// Each poll is issued ~1,500 cy (the other direction's dot+act) before its
// check -> RT overlaps compute. Publishes precede all blocking waits (no
// deadlock); skew <= 1 iter; 2-buffer mailbox + 1-bit tag (bit0 of mantissa,
// <=1 ulp) distinguishes i from i-2. Poison 0xAA bit0=0 != initial tag 1.
__global__ __launch_bounds__(64) void lstm_kernel(
    const float* __restrict__ pre_f, const float* __restrict__ pre_b,
    const float* __restrict__ whh_f, const float* __restrict__ whh_b,
    const float* __restrict__ h0_f, const float* __restrict__ c0_f,
    const float* __restrict__ h0_b, const float* __restrict__ c0_b,
    float* __restrict__ hs_f, float* __restrict__ hs_b,
    unsigned* __restrict__ mbox)
{
    const int cb = blockIdx.x;             // 0..31
    const int cell0 = cb * 8;

    const int l = threadIdx.x;       // 0..63
    const int r = l >> 1;            // local row 0..31 (gate-major)
    const int half = l & 1;          // k-half
    const int g = r >> 3, cl = r & 7;
    const int grow = g * 256 + cell0 + cl;   // global gate row

    __shared__ __align__(16) float4 wf4[32 * 64];   // 32 KB
    __shared__ __align__(16) float4 wb4[32 * 64];   // 32 KB
    __shared__ __align__(16) float  hf_lds[256];
    __shared__ __align__(16) float  hb_lds[256];

    {
        const float4* sf = (const float4*)(whh_f + (size_t)grow * H2N + half * 128);
        const float4* sb = (const float4*)(whh_b + (size_t)grow * H2N + half * 128);
#pragma unroll
        for (int j = 0; j < 32; j++) { wf4[j * 64 + l] = sf[j]; wb4[j * 64 + l] = sb[j]; }
    }
    ((float4*)hf_lds)[l] = ((const float4*)h0_f)[l];
    ((float4*)hb_lds)[l] = ((const float4*)h0_b)[l];
    float c_f = (l < 8) ? c0_f[cell0 + l] : 0.f;
    float c_b = (l < 8) ? c0_b[cell0 + l] : 0.f;
    __syncthreads();

    const float* pf_base = pre_f + grow;
    const float* pb_base = pre_b + grow;
    float pf_cur = (half == 0) ? pf_base[0] : 0.f;
    float pb_cur = (half == 0) ? pb_base[0] : 0.f;
    const int ai = l & 7;
    unsigned* mbf = mbox;          // [2][256]
    unsigned* mbb = mbox + 512;    // [2][256]

    uint4 vf = {0, 0, 0, 0}, vb = {0, 0, 0, 0};

    for (int i = 0; i < SLEN; i++) {
        const unsigned etag = (((unsigned)i >> 1) & 1u) ^ 1u;
        unsigned* mbf_cur = mbf + (i & 1) * 256;
        unsigned* mbb_cur = mbb + (i & 1) * 256;

        // ---- (A) complete h_b(i-1): check speculative vb, retry if early ----
        if (i > 0) {
            const unsigned ptag = (((unsigned)(i - 1) >> 1) & 1u) ^ 1u;
            const unsigned* src = mbb + ((i - 1) & 1) * 256 + 4 * l;
            int spin = 0;
            while ((((vb.x ^ ptag) | (vb.y ^ ptag) | (vb.z ^ ptag) | (vb.w ^ ptag)) & 1u)
                   && ++spin < 2000000) {
                vb.x = aload(src + 0); vb.y = aload(src + 1);
                vb.z = aload(src + 2); vb.w = aload(src + 3);
            }
            float4 hv; hv.x = __uint_as_float(vb.x); hv.y = __uint_as_float(vb.y);
            hv.z = __uint_as_float(vb.z); hv.w = __uint_as_float(vb.w);
            *(float4*)(hb_lds + 4 * l) = hv;
            lds_fence();
        }

        // ---- (B) dot_b + act_b + publish h_b(i) ----
        float pb_next = (half == 0 && i < SLEN - 1) ? pb_base[(size_t)(i + 1) * G4] : 0.f;
        {
            float a0 = pb_cur, a1 = 0.f, a2 = 0.f, a3 = 0.f;
            const float4* hrow4 = (const float4*)(hb_lds + half * 128);
#pragma unroll
            for (int j = 0; j < 32; j++) {
                float4 wv = wb4[j * 64 + l];
                float4 hv = hrow4[j];
                a0 += wv.x * hv.x; a1 += wv.y * hv.y;
                a2 += wv.z * hv.z; a3 += wv.w * hv.w;
            }
            float sum = (a0 + a1) + (a2 + a3);
            sum += __shfl_xor(sum, 1, 64);
            float s_i = __shfl(sum, 2 * ai, 64);
            float s_f = __shfl(sum, 16 + 2 * ai, 64);
            float s_g = __shfl(sum, 32 + 2 * ai, 64);
            float s_o = __shfl(sum, 48 + 2 * ai, 64);
            if (l < 8) {
                float i_ = fast_sigmoid(s_i);
                float f_ = fast_sigmoid(s_f);
                float g_ = fast_tanh(s_g);
                float o_ = fast_sigmoid(s_o);
                c_b = f_ * c_b + i_ * g_;
                float h = o_ * fast_tanh(c_b);
                unsigned hm = (__float_as_uint(h) & ~1u) | etag;
                __hip_atomic_store(mbb_cur + cell0 + l, hm,
                                   __ATOMIC_RELAXED, __HIP_MEMORY_SCOPE_AGENT);
                __builtin_nontemporal_store(hm, (unsigned*)hs_b + (size_t)i * H2N + cell0 + l);
            }
        }
        // ---- (C) issue speculative poll for h_b(i) (checked next iter A) ----
        {
            const unsigned* s = mbb_cur + 4 * l;
            vb.x = aload(s + 0); vb.y = aload(s + 1);
            vb.z = aload(s + 2); vb.w = aload(s + 3);
        }

        // ---- (D) complete h_f(i-1) ----
        if (i > 0) {
            const unsigned ptag = (((unsigned)(i - 1) >> 1) & 1u) ^ 1u;
            const unsigned* src = mbf + ((i - 1) & 1) * 256 + 4 * l;
            int spin = 0;
            while ((((vf.x ^ ptag) | (vf.y ^ ptag) | (vf.z ^ ptag) | (vf.w ^ ptag)) & 1u)
                   && ++spin < 2000000) {
                vf.x = aload(src + 0); vf.y = aload(src + 1);
                vf.z = aload(src + 2); vf.w = aload(src + 3);
            }
            float4 hv; hv.x = __uint_as_float(vf.x); hv.y = __uint_as_float(vf.y);
            hv.z = __uint_as_float(vf.z); hv.w = __uint_as_float(vf.w);
            *(float4*)(hf_lds + 4 * l) = hv;
            lds_fence();
        }

        // ---- (E) dot_f + act_f + publish h_f(i) ----
        float pf_next = (half == 0 && i < SLEN - 1) ? pf_base[(size_t)(i + 1) * G4] : 0.f;
        {
            float a0 = pf_cur, a1 = 0.f, a2 = 0.f, a3 = 0.f;
            const float4* hrow4 = (const float4*)(hf_lds + half * 128);
#pragma unroll
            for (int j = 0; j < 32; j++) {
                float4 wv = wf4[j * 64 + l];
                float4 hv = hrow4[j];
                a0 += wv.x * hv.x; a1 += wv.y * hv.y;
                a2 += wv.z * hv.z; a3 += wv.w * hv.w;
            }
            float sum = (a0 + a1) + (a2 + a3);
            sum += __shfl_xor(sum, 1, 64);
            float s_i = __shfl(sum, 2 * ai, 64);
            float s_f = __shfl(sum, 16 + 2 * ai, 64);
            float s_g = __shfl(sum, 32 + 2 * ai, 64);
            float s_o = __shfl(sum, 48 + 2 * ai, 64);
            if (l < 8) {
                float i_ = fast_sigmoid(s_i);
                float f_ = fast_sigmoid(s_f);
                float g_ = fast_tanh(s_g);
                float o_ = fast_sigmoid(s_o);
                c_f = f_ * c_f + i_ * g_;
                float h = o_ * fast_tanh(c_f);
                unsigned hm = (__float_as_uint(h) & ~1u) | etag;
                __hip_atomic_store(mbf_cur + cell0 + l, hm,
                                   __ATOMIC_RELAXED, __HIP_MEMORY_SCOPE_AGENT);
                __builtin_nontemporal_store(hm, (unsigned*)hs_f + (size_t)i * H2N + cell0 + l);
            }
        }
        // ---- (F) issue speculative poll for h_f(i) ----
        {
            const unsigned* s = mbf_cur + 4 * l;
            vf.x = aload(s + 0); vf.y = aload(s + 1);
            vf.z = aload(s + 2); vf.w = aload(s + 3);
        }

        pb_cur = pb_next;
        pf_cur = pf_next;
    }
}

// ---------------- K3: feats = concat(hs_f[s], hs_b[S-1-s]) @ w_out^T + b_out ----------------
__global__ __launch_bounds__(256) void feats_kernel(
    const float* __restrict__ hs_f, const float* __restrict__ hs_b,
    const float* __restrict__ w_out, const float* __restrict__ b_out,
    float* __restrict__ feats)
{
    const int rs0 = blockIdx.x * 16;
    const int tid = threadIdx.x;
    const int r = tid >> 4, cc = tid & 15;

    __shared__ float Hs[16][516];
    for (int i = tid; i < 16 * 256; i += 256) {
        int rr = i >> 8, k = i & 255;
        Hs[rr][k]       = hs_f[(size_t)(rs0 + rr) * H2N + k];
        Hs[rr][256 + k] = hs_b[(size_t)(SLEN - 1 - (rs0 + rr)) * H2N + k];
    }
    __syncthreads();

    float acc = 0.f;
    const float* wr = w_out + (size_t)cc * 512;
    const float* hrow = Hs[r];
#pragma unroll 4
    for (int kq = 0; kq < 128; kq++) {
        float4 hv = *(const float4*)(hrow + 4 * kq);
        float4 wv = *(const float4*)(wr + 4 * kq);
        acc += hv.x * wv.x; acc += hv.y * wv.y;
        acc += hv.z * wv.z; acc += hv.w * wv.w;
    }
    feats[(size_t)(rs0 + r) * NTAG + cc] = acc + b_out[cc];
}

// ---------------- K4: Viterbi scan + backtrack (single wave, LDS back-ptrs) ----------------
__global__ __launch_bounds__(64) void viterbi_kernel(
    const float* __restrict__ feats, const float* __restrict__ trans,
    float* __restrict__ out)
{
    __shared__ unsigned char back_s[SLEN * 8];   // nibble-packed backpointers

    const int lane = threadIdx.x;
    const int nx = lane >> 2, pc = lane & 3;

    float tr[4];
#pragma unroll
    for (int j = 0; j < 4; j++) tr[j] = trans[nx * NTAG + pc * 4 + j];

    float sc = (nx == 0) ? 0.f : NEGV;
    float fe = feats[nx];

    for (int t = 0; t < SLEN; t++) {
        float fe_next = (t < SLEN - 1) ? feats[(size_t)(t + 1) * NTAG + nx] : 0.f;

        float bv; int bi;
#pragma unroll
        for (int j = 0; j < 4; j++) {
            float s = __shfl(sc, 4 * (pc * 4 + j), 64);
            float cand = s + tr[j];
            if (j == 0) { bv = cand; bi = pc * 4; }
            else if (cand > bv) { bv = cand; bi = pc * 4 + j; }
        }
#pragma unroll
        for (int off = 1; off < 4; off <<= 1) {
            float ov = __shfl_xor(bv, off, 64);
            int   oi = __shfl_xor(bi, off, 64);
            if (ov > bv || (ov == bv && oi < bi)) { bv = ov; bi = oi; }
        }
        int bi_part = __shfl(bi, (nx | 1) * 4, 64);
        if (pc == 0 && (nx & 1) == 0)
            back_s[t * 8 + (nx >> 1)] = (unsigned char)((bi & 15) | (bi_part << 4));
        sc = bv + fe;
        fe = fe_next;
    }

    float bestv = 0.f; int besti = 0;
#pragma unroll
    for (int j = 0; j < NTAG; j++) {
        float sj = __shfl(sc, 4 * j, 64);
        float fj = sj + trans[1 * NTAG + j];
        if (j == 0) { bestv = fj; besti = 0; }
        else if (fj > bestv) { bestv = fj; besti = j; }
    }
    __syncthreads();

    if (lane == 0) {
        out[0] = bestv;
        int cur = besti;
        for (int t = SLEN - 1; t >= 1; t--) {
            out[1 + t] = (float)cur;
            unsigned char byte = back_s[t * 8 + (cur >> 1)];
            cur = (cur & 1) ? (byte >> 4) : (byte & 15);
        }
        out[1] = (float)cur;
    }
}

extern "C" void kernel_launch(void* const* d_in, const int* in_sizes, int n_in,
                              void* d_out, int out_size, void* d_ws, size_t ws_size,
                              hipStream_t stream) {
    const int*   sent   = (const int*)d_in[0];
    const float* emb    = (const float*)d_in[1];
    const float* w_ih_f = (const float*)d_in[2];
    const float* w_hh_f = (const float*)d_in[3];
    const float* b_f    = (const float*)d_in[4];
    const float* w_ih_b = (const float*)d_in[5];
    const float* w_hh_b = (const float*)d_in[6];
    const float* b_b    = (const float*)d_in[7];
    const float* h0_f   = (const float*)d_in[8];
    const float* c0_f   = (const float*)d_in[9];
    const float* h0_b   = (const float*)d_in[10];
    const float* c0_b   = (const float*)d_in[11];
    const float* w_out  = (const float*)d_in[12];
    const float* b_out  = (const float*)d_in[13];
    const float* trans  = (const float*)d_in[14];
    float* out = (float*)d_out;

    if (ws_size < WS_NEEDED) return;  // visible failure, no OOB writes

    float* ws = (float*)d_ws;
    float* pre_f = ws + OFF_PRE_F;
    float* pre_b = ws + OFF_PRE_B;
    float* hs_f  = ws + OFF_HS_F;
    float* hs_b  = ws + OFF_HS_B;
    float* feats = ws + OFF_FEATS;
    unsigned* mbox = (unsigned*)(ws + OFF_MBOX);

    gemm_pre<<<dim3(128, 16, 2), 256, 0, stream>>>(sent, emb, w_ih_f, b_f, w_ih_b, b_b, pre_f, pre_b);
    lstm_kernel<<<32, 64, 0, stream>>>(pre_f, pre_b, w_hh_f, w_hh_b,
                                       h0_f, c0_f, h0_b, c0_b, hs_f, hs_b, mbox);
    feats_kernel<<<512, 256, 0, stream>>>(hs_f, hs_b, w_out, b_out, feats);
    viterbi_kernel<<<1, 64, 0, stream>>>(feats, trans, out);
}

// Round 10
// 29313.058 us; speedup vs baseline: 1.1138x; 1.1138x over previous
//
#include <hip/hip_runtime.h>
#include <math.h>

#define SLEN 8192
#define DIM  256
#define H2N  256
#define G4   1024
#define NTAG 16
#define NEGV (-10000.0f)

// ws layout (float offsets unless noted)
#define OFF_PRE_F   0
#define OFF_PRE_B   (SLEN*G4)
#define OFF_HS_F    (2*SLEN*G4)
#define OFF_HS_B    (2*SLEN*G4 + SLEN*H2N)
#define OFF_FEATS   (2*SLEN*G4 + 2*SLEN*H2N)
#define OFF_CNT     (OFF_FEATS + SLEN*NTAG)      // [2][SLEN] ints
#define WS_NEEDED   ((size_t)(OFF_CNT + 2*SLEN) * 4)

// ---------------- K1: pre = gather(emb, sentence[±]) @ w_ih^T + b ----------------
__global__ __launch_bounds__(256) void gemm_pre(
    const int* __restrict__ sent, const float* __restrict__ emb,
    const float* __restrict__ wf, const float* __restrict__ bf,
    const float* __restrict__ wb, const float* __restrict__ bb,
    float* __restrict__ pre_f, float* __restrict__ pre_b)
{
    const int dir = blockIdx.z;
    const float* w    = dir ? wb : wf;
    const float* bias = dir ? bb : bf;
    float* out        = dir ? pre_b : pre_f;
    const int m0 = blockIdx.x * 64, n0 = blockIdx.y * 64;

    __shared__ float As[16][68];   // [k][m]
    __shared__ float Bs[16][68];   // [k][n]
    __shared__ int   sidx[64];

    const int tid = threadIdx.x;
    const int tx = tid & 15, ty = tid >> 4;

    if (tid < 64) {
        int m = m0 + tid;
        int pos = dir ? (SLEN - 1 - m) : m;
        sidx[tid] = sent[pos];
    }
    __syncthreads();

    float acc[4][4];
#pragma unroll
    for (int i = 0; i < 4; i++)
#pragma unroll
        for (int j = 0; j < 4; j++) acc[i][j] = 0.f;

    const int lr = tid >> 2, lc = (tid & 3) * 4;

    for (int k0 = 0; k0 < DIM; k0 += 16) {
        float4 av = *(const float4*)(emb + (size_t)sidx[lr] * DIM + k0 + lc);
        float4 bv = *(const float4*)(w + (size_t)(n0 + lr) * DIM + k0 + lc);
        As[lc+0][lr] = av.x; As[lc+1][lr] = av.y; As[lc+2][lr] = av.z; As[lc+3][lr] = av.w;
        Bs[lc+0][lr] = bv.x; Bs[lc+1][lr] = bv.y; Bs[lc+2][lr] = bv.z; Bs[lc+3][lr] = bv.w;
        __syncthreads();
#pragma unroll
        for (int k = 0; k < 16; k++) {
            float4 a4 = *(const float4*)&As[k][ty * 4];
            float4 b4 = *(const float4*)&Bs[k][tx * 4];
            float a[4] = {a4.x, a4.y, a4.z, a4.w};
            float b[4] = {b4.x, b4.y, b4.z, b4.w};
#pragma unroll
            for (int i = 0; i < 4; i++)
#pragma unroll
                for (int j = 0; j < 4; j++) acc[i][j] += a[i] * b[j];
        }
        __syncthreads();
    }

    float4 b4 = *(const float4*)(bias + n0 + tx*4);
#pragma unroll
    for (int i = 0; i < 4; i++) {
        float4 v;
        v.x = acc[i][0] + b4.x; v.y = acc[i][1] + b4.y;
        v.z = acc[i][2] + b4.z; v.w = acc[i][3] + b4.w;
        *(float4*)(out + (size_t)(m0 + ty*4 + i) * G4 + n0 + tx*4) = v;
    }
}

__device__ __forceinline__ float fast_sigmoid(float x) {
    return 1.f / (1.f + __expf(-x));
}
__device__ __forceinline__ float fast_tanh(float x) {
    float xc = fminf(fmaxf(x, -15.f), 15.f);
    float e = __expf(2.f * xc);
    return (e - 1.f) / (e + 1.f);
}
__device__ __forceinline__ unsigned aload(const unsigned* p) {
    return __hip_atomic_load(p, __ATOMIC_RELAXED, __HIP_MEMORY_SCOPE_AGENT);
}

// ---------------- K2: two LSTMs, counter-gated exchange ----------------
// R9 lesson: hand-rolled sc0 cache-op semantics hung the GPU -> only
// compiler-emitted memory ordering from here on.
// R7 analysis: sync ~4,000 cy/step, suspected poll contention (64 waves x 4
// scattered atomic dwords re-loaded every spin round, serialized at LLC).
// R10 protocol per step t:
//   producers (lanes 0..7): agent-relaxed store h (EXACT, no tag bit)
//     directly into hs[t]; lane 0 then does ONE release atomicAdd on
//     cnt[dir][t] (release = compiler emits vmcnt drain -> h at LLC first).
//   consumers: relaxed spin on cnt[dir][t] (one dword; 64 lanes same addr =
//     1 request/round) until ==32, one acquire fence, then the 4 data loads
//     are issued EXACTLY ONCE (1 RT, never spun).
// Fresh counter per t -> no ABA; cnt zeroed in-graph; publishes precede all
// waits -> deadlock-free; spin caps bound worst-case time.
__global__ __launch_bounds__(64) void lstm_kernel(
    const float* __restrict__ pre_f, const float* __restrict__ pre_b,
    const float* __restrict__ whh_f, const float* __restrict__ whh_b,
    const float* __restrict__ h0_f, const float* __restrict__ c0_f,
    const float* __restrict__ h0_b, const float* __restrict__ c0_b,
    float* __restrict__ hs_f, float* __restrict__ hs_b,
    int* __restrict__ cnt_base)
{
    const int blk = blockIdx.x;            // 0..63
    const int d = blk >> 5, cb = blk & 31; // direction, cell-block
    const int cell0 = cb * 8;
    const float* pre = d ? pre_b : pre_f;
    const float* whh = d ? whh_b : whh_f;
    const float* h0  = d ? h0_b : h0_f;
    const float* c0  = d ? c0_b : c0_f;
    float* hs        = d ? hs_b : hs_f;
    int* cnt         = cnt_base + d * SLEN;

    const int l = threadIdx.x;       // 0..63
    const int r = l >> 1;            // local row 0..31 (gate-major)
    const int half = l & 1;          // k-half
    const int g = r >> 3, cl = r & 7;
    const int grow = g * 256 + cell0 + cl;   // global gate row

    __shared__ __align__(16) float4 w_pack4[32 * 64];   // 32 KB, [j][lane]
    __shared__ __align__(16) float  h_lds[256];

    {
        const float4* src = (const float4*)(whh + (size_t)grow * H2N + half * 128);
#pragma unroll
        for (int j = 0; j < 32; j++) w_pack4[j * 64 + l] = src[j];
    }
    ((float4*)h_lds)[l] = ((const float4*)h0)[l];
    float c = (l < 8) ? c0[cell0 + l] : 0.f;
    __syncthreads();

    const float* pre_base = pre + grow;
    float pre_cur = (half == 0) ? pre_base[0] : 0.f;
    const int ai = l & 7;            // activation cell index (lanes 0..7)

    for (int t = 0; t < SLEN; t++) {
        float pre_next = (half == 0 && t < SLEN - 1) ? pre_base[(size_t)(t + 1) * G4] : 0.f;

        // dot over this thread's k-half: w + h from LDS (conflict-free)
        float a0 = pre_cur, a1 = 0.f, a2 = 0.f, a3 = 0.f;
        const float4* hrow4 = (const float4*)(h_lds + half * 128);
#pragma unroll
        for (int j = 0; j < 32; j++) {
            float4 wv = w_pack4[j * 64 + l];
            float4 hv = hrow4[j];
            a0 += wv.x * hv.x; a1 += wv.y * hv.y;
            a2 += wv.z * hv.z; a3 += wv.w * hv.w;
        }
        float sum = (a0 + a1) + (a2 + a3);
        sum += __shfl_xor(sum, 1, 64);   // row r total at lanes 2r, 2r+1

        // gate sums for cell ai: rows ai, 8+ai, 16+ai, 24+ai
        float s_i = __shfl(sum, 2 * ai, 64);
        float s_f = __shfl(sum, 16 + 2 * ai, 64);
        float s_g = __shfl(sum, 32 + 2 * ai, 64);
        float s_o = __shfl(sum, 48 + 2 * ai, 64);

        if (l < 8) {
            float i_ = fast_sigmoid(s_i);
            float f_ = fast_sigmoid(s_f);
            float g_ = fast_tanh(s_g);
            float o_ = fast_sigmoid(s_o);
            c = f_ * c + i_ * g_;
            float h = o_ * fast_tanh(c);
            __hip_atomic_store((unsigned*)hs + (size_t)t * H2N + cell0 + l,
                               __float_as_uint(h),
                               __ATOMIC_RELAXED, __HIP_MEMORY_SCOPE_AGENT);
        }
        if (l == 0) {
            // release: drains the 8 h-stores to LLC, then bumps the counter
            __hip_atomic_fetch_add(&cnt[t], 1,
                                   __ATOMIC_RELEASE, __HIP_MEMORY_SCOPE_AGENT);
        }

        // single-dword detection spin, then ONE data round
        {
            int v, sp = 0;
            do {
                v = __hip_atomic_load(&cnt[t], __ATOMIC_RELAXED, __HIP_MEMORY_SCOPE_AGENT);
            } while (v < 32 && ++sp < 50000);
            __builtin_amdgcn_fence(__ATOMIC_ACQUIRE, "agent");

            const unsigned* hsrc = (const unsigned*)hs + (size_t)t * H2N + 4 * l;
            unsigned v0 = aload(hsrc + 0), v1 = aload(hsrc + 1);
            unsigned v2 = aload(hsrc + 2), v3 = aload(hsrc + 3);
            float4 hv4;
            hv4.x = __uint_as_float(v0); hv4.y = __uint_as_float(v1);
            hv4.z = __uint_as_float(v2); hv4.w = __uint_as_float(v3);
            *(float4*)(h_lds + 4 * l) = hv4;
        }
        __syncthreads();             // single wave: lgkm drain + barrier
        pre_cur = pre_next;
    }
}

// ---------------- K3: feats = concat(hs_f[s], hs_b[S-1-s]) @ w_out^T + b_out ----------------
__global__ __launch_bounds__(256) void feats_kernel(
    const float* __restrict__ hs_f, const float* __restrict__ hs_b,
    const float* __restrict__ w_out, const float* __restrict__ b_out,
    float* __restrict__ feats)
{
    const int rs0 = blockIdx.x * 16;
    const int tid = threadIdx.x;
    const int r = tid >> 4, cc = tid & 15;

    __shared__ float Hs[16][516];
    for (int i = tid; i < 16 * 256; i += 256) {
        int rr = i >> 8, k = i & 255;
        Hs[rr][k]       = hs_f[(size_t)(rs0 + rr) * H2N + k];
        Hs[rr][256 + k] = hs_b[(size_t)(SLEN - 1 - (rs0 + rr)) * H2N + k];
    }
    __syncthreads();

    float acc = 0.f;
    const float* wr = w_out + (size_t)cc * 512;
    const float* hrow = Hs[r];
#pragma unroll 4
    for (int kq = 0; kq < 128; kq++) {
        float4 hv = *(const float4*)(hrow + 4 * kq);
        float4 wv = *(const float4*)(wr + 4 * kq);
        acc += hv.x * wv.x; acc += hv.y * wv.y;
        acc += hv.z * wv.z; acc += hv.w * wv.w;
    }
    feats[(size_t)(rs0 + r) * NTAG + cc] = acc + b_out[cc];
}

// ---------------- K4: Viterbi scan + backtrack (single wave, LDS back-ptrs) ----------------
__global__ __launch_bounds__(64) void viterbi_kernel(
    const float* __restrict__ feats, const float* __restrict__ trans,
    float* __restrict__ out)
{
    __shared__ unsigned char back_s[SLEN * 8];   // nibble-packed backpointers

    const int lane = threadIdx.x;
    const int nx = lane >> 2, pc = lane & 3;

    float tr[4];
#pragma unroll
    for (int j = 0; j < 4; j++) tr[j] = trans[nx * NTAG + pc * 4 + j];

    float sc = (nx == 0) ? 0.f : NEGV;
    float fe = feats[nx];

    for (int t = 0; t < SLEN; t++) {
        float fe_next = (t < SLEN - 1) ? feats[(size_t)(t + 1) * NTAG + nx] : 0.f;

        float bv; int bi;
#pragma unroll
        for (int j = 0; j < 4; j++) {
            float s = __shfl(sc, 4 * (pc * 4 + j), 64);
            float cand = s + tr[j];
            if (j == 0) { bv = cand; bi = pc * 4; }
            else if (cand > bv) { bv = cand; bi = pc * 4 + j; }
        }
#pragma unroll
        for (int off = 1; off < 4; off <<= 1) {
            float ov = __shfl_xor(bv, off, 64);
            int   oi = __shfl_xor(bi, off, 64);
            if (ov > bv || (ov == bv && oi < bi)) { bv = ov; bi = oi; }
        }
        int bi_part = __shfl(bi, (nx | 1) * 4, 64);
        if (pc == 0 && (nx & 1) == 0)
            back_s[t * 8 + (nx >> 1)] = (unsigned char)((bi & 15) | (bi_part << 4));
        sc = bv + fe;
        fe = fe_next;
    }

    float bestv = 0.f; int besti = 0;
#pragma unroll
    for (int j = 0; j < NTAG; j++) {
        float sj = __shfl(sc, 4 * j, 64);
        float fj = sj + trans[1 * NTAG + j];
        if (j == 0) { bestv = fj; besti = 0; }
        else if (fj > bestv) { bestv = fj; besti = j; }
    }
    __syncthreads();

    if (lane == 0) {
        out[0] = bestv;
        int cur = besti;
        for (int t = SLEN - 1; t >= 1; t--) {
            out[1 + t] = (float)cur;
            unsigned char byte = back_s[t * 8 + (cur >> 1)];
            cur = (cur & 1) ? (byte >> 4) : (byte & 15);
        }
        out[1] = (float)cur;
    }
}

extern "C" void kernel_launch(void* const* d_in, const int* in_sizes, int n_in,
                              void* d_out, int out_size, void* d_ws, size_t ws_size,
                              hipStream_t stream) {
    const int*   sent   = (const int*)d_in[0];
    const float* emb    = (const float*)d_in[1];
    const float* w_ih_f = (const float*)d_in[2];
    const float* w_hh_f = (const float*)d_in[3];
    const float* b_f    = (const float*)d_in[4];
    const float* w_ih_b = (const float*)d_in[5];
    const float* w_hh_b = (const float*)d_in[6];
    const float* b_b    = (const float*)d_in[7];
    const float* h0_f   = (const float*)d_in[8];
    const float* c0_f   = (const float*)d_in[9];
    const float* h0_b   = (const float*)d_in[10];
    const float* c0_b   = (const float*)d_in[11];
    const float* w_out  = (const float*)d_in[12];
    const float* b_out  = (const float*)d_in[13];
    const float* trans  = (const float*)d_in[14];
    float* out = (float*)d_out;

    if (ws_size < WS_NEEDED) return;  // visible failure, no OOB writes

    float* ws = (float*)d_ws;
    float* pre_f = ws + OFF_PRE_F;
    float* pre_b = ws + OFF_PRE_B;
    float* hs_f  = ws + OFF_HS_F;
    float* hs_b  = ws + OFF_HS_B;
    float* feats = ws + OFF_FEATS;
    int* cnt = (int*)(ws + OFF_CNT);

    hipMemsetAsync(cnt, 0, 2 * SLEN * sizeof(int), stream);

    gemm_pre<<<dim3(128, 16, 2), 256, 0, stream>>>(sent, emb, w_ih_f, b_f, w_ih_b, b_b, pre_f, pre_b);
    lstm_kernel<<<64, 64, 0, stream>>>(pre_f, pre_b, w_hh_f, w_hh_b,
                                       h0_f, c0_f, h0_b, c0_b, hs_f, hs_b, cnt);
    feats_kernel<<<512, 256, 0, stream>>>(hs_f, hs_b, w_out, b_out, feats);
    viterbi_kernel<<<1, 64, 0, stream>>>(feats, trans, out);
}